// Round 6
// baseline (486.376 us; speedup 1.0000x reference)
//
#include <hip/hip_runtime.h>
#include <hip/hip_bf16.h>

namespace {

constexpr int kCin   = 128;
constexpr int kHW    = 12544;   // 112*112
constexpr int kW     = 112;
constexpr int kGrps  = 49;      // output kernel: 49 blocks * 256 tokens per image
constexpr int kTiles = 196;     // main kernel: 196 blocks * 64 tokens per image
constexpr size_t kOut1Off = (size_t)16 * 128 * kHW;  // element offset of assignment map

typedef __attribute__((ext_vector_type(8))) short short8;   // 8 bf16 = 4 VGPR (MFMA A/B frag)
typedef __attribute__((ext_vector_type(4))) float f32x4;    // MFMA C/D frag

__device__ __forceinline__ float bf2f(unsigned short u) {
  union { unsigned int i; float f; } v;
  v.i = ((unsigned int)u) << 16;
  return v.f;
}

__device__ __forceinline__ unsigned short f2bf(float f) {
  union { float f; unsigned int i; } v;
  v.f = f;
  unsigned int x = v.i;
  x += 0x7fffu + ((x >> 16) & 1u);   // RNE
  return (unsigned short)(x >> 16);
}

// ---- dtype-templated load/store helpers (BF=true: bf16, else fp32) ----
template <bool BF>
__device__ __forceinline__ float ld1(const void* p, size_t i) {
  if constexpr (BF) return bf2f(((const unsigned short*)p)[i]);
  else              return ((const float*)p)[i];
}
template <bool BF>
__device__ __forceinline__ void ld4(const void* p, size_t i, float o[4]) {
  if constexpr (BF) {
    const ushort4 u = *reinterpret_cast<const ushort4*>((const unsigned short*)p + i);
    o[0] = bf2f(u.x); o[1] = bf2f(u.y); o[2] = bf2f(u.z); o[3] = bf2f(u.w);
  } else {
    const float4 u = *reinterpret_cast<const float4*>((const float*)p + i);
    o[0] = u.x; o[1] = u.y; o[2] = u.z; o[3] = u.w;
  }
}
template <bool BF>
__device__ __forceinline__ void st1(void* p, size_t i, float v) {
  if constexpr (BF) ((unsigned short*)p)[i] = f2bf(v);
  else              ((float*)p)[i] = v;
}
template <bool BF>
__device__ __forceinline__ void st4(void* p, size_t i, const float v[4]) {
  if constexpr (BF) {
    ushort4 u;
    u.x = f2bf(v[0]); u.y = f2bf(v[1]); u.z = f2bf(v[2]); u.w = f2bf(v[3]);
    *reinterpret_cast<ushort4*>((unsigned short*)p + i) = u;
  } else {
    float4 u;
    u.x = v[0]; u.y = v[1]; u.z = v[2]; u.w = v[3];
    *reinterpret_cast<float4*>((float*)p + i) = u;
  }
}

// ---------------------------------------------------------------------------
// Kernel 0: detect input dtype. bf16 f_w values are ~N(0, 0.09): none exceed 4.
// fp32 f_w read as bf16 pairs: ~25% of ushorts are mantissa garbage with
// uniform-random exponent -> |v|>4 for ~half of those. flag=1 means bf16.
// ---------------------------------------------------------------------------
__global__ void detect_dtype(const unsigned short* __restrict__ fw, int* __restrict__ flag) {
  __shared__ int cnt_s;
  if (threadIdx.x == 0) cnt_s = 0;
  __syncthreads();
  int c = 0;
  for (int i = threadIdx.x; i < 4096; i += 256) {
    const float v = bf2f(fw[i]);
    if (fabsf(v) > 4.0f) ++c;
  }
  atomicAdd(&cnt_s, c);
  __syncthreads();
  if (threadIdx.x == 0) flag[0] = (cnt_s > 100) ? 0 : 1;
}

// ---------------------------------------------------------------------------
// Kernel 1: ONE 64-token tile per block (grid 16*196=3136).
// bf16 path: phase A on the MATRIX cores. C[192 rows f;v][64 tok] =
// W[192x128] x X[128x64] via mfma_f32_16x16x32_bf16. 4 waves, wave w owns
// rows [w*48, w*48+48). A-frags (W) load straight from global (lane l&15 =
// row, 8 contiguous channels at (l>>4)*8 — 16B, L2-hot, no block-level
// redundancy). X staged transposed in LDS (xt[64][136] bf16, 16B-aligned
// stride) so B-frags are single ds_read_b128. MFMA count: 48/wave — the
// 9.87 GFLOP that pinned VALU at ~300us becomes ~free.
// Verified layouts (learn_hip m89/m91): A row=l&15,k=(l>>4)*8+j;
// B col=l&15,k=(l>>4)*8+j; D col=l&15,row=(l>>4)*4+reg.
// fp32 path: R3's direct-global VALU GEMM (proven, off the bench path).
// ---------------------------------------------------------------------------
struct alignas(16) SMain {
  union {
    unsigned short xt[64][136];  // 17408 B: X^T (bf16 MFMA path only)
    float fh[96 * 65];           // 24960 B: f rows (B1), then v rows (B2)
  } u;
  float cn[4][24];
  float s[4][64];
  unsigned char idx[4][64];
  unsigned char q[64];
};

template <bool BF>
__device__ __forceinline__ void main_body(
    SMain& sm,
    const void* __restrict__ x,  const void* __restrict__ f_w, const void* __restrict__ f_b,
    const void* __restrict__ v_w, const void* __restrict__ v_b,
    const void* __restrict__ sim_alpha, const void* __restrict__ sim_beta,
    const void* __restrict__ centers,
    void* __restrict__ out0,
    float* __restrict__ aggsum, float* __restrict__ vpool, float* __restrict__ cnt)
{
  const int tid  = threadIdx.x;
  const int b    = blockIdx.x / kTiles;
  const int tile = blockIdx.x % kTiles;
  const int hw0  = tile * 64;

  if (tid < 4) {
    float cv[24];
    float n2 = 0.f;
#pragma unroll
    for (int c = 0; c < 24; ++c) { cv[c] = ld1<BF>(centers, tid * 24 + c); n2 += cv[c] * cv[c]; }
    const float inv = 1.f / fmaxf(sqrtf(n2), 1e-12f);
#pragma unroll
    for (int c = 0; c < 24; ++c) sm.cn[tid][c] = cv[c] * inv;
  }
  const float alpha = ld1<BF>(sim_alpha, 0);
  const float beta  = ld1<BF>(sim_beta, 0);

  const int e   = tid >> 6;
  const int tok = tid & 63;

  // ---- BF (MFMA) path state ----
  const int lane = tid & 63;
  const int wv   = tid >> 6;       // wave 0..3
  const int qq   = lane >> 4;      // 0..3
  const int tt   = lane & 15;
  f32x4 accB[3][4];
  float biasB[3][4];
  int   wrb = 0;
  bool  isfB = true;

  // ---- fp32 (VALU) path state ----
  const int ty = tid >> 4;
  const int tx = tid & 15;
  const bool is_f = (ty < 8);
  float acc[12][4];
  float bias[12];

  if constexpr (BF) {
    // ---- stage X^T: xt[tok][ch], 128 ch, stride 136 (16B-aligned rows) ----
#pragma unroll
    for (int s5 = 0; s5 < 8; ++s5) {
      const int id2 = tid + s5 * 256;      // 0..2047: 128 ch x 16 token-groups
      const int ch  = id2 >> 4;
      const int tg  = id2 & 15;
      const ushort4 u4 = *reinterpret_cast<const ushort4*>(
          (const unsigned short*)x + ((size_t)b * kCin + ch) * kHW + hw0 + tg * 4);
      sm.u.xt[tg * 4 + 0][ch] = u4.x;
      sm.u.xt[tg * 4 + 1][ch] = u4.y;
      sm.u.xt[tg * 4 + 2][ch] = u4.z;
      sm.u.xt[tg * 4 + 3][ch] = u4.w;
    }
    const int wbase = wv * 48;
    isfB = (wv < 2);
    const unsigned short* wselB = (const unsigned short*)(isfB ? f_w : v_w);
    const void* bselB = isfB ? f_b : v_b;
    wrb = isfB ? wbase : wbase - 96;
#pragma unroll
    for (int rt = 0; rt < 3; ++rt)
#pragma unroll
      for (int rg = 0; rg < 4; ++rg)
        biasB[rt][rg] = ld1<true>(bselB, (size_t)(wrb + rt * 16 + qq * 4 + rg));
    __syncthreads();

    const f32x4 z4 = {0.f, 0.f, 0.f, 0.f};
#pragma unroll
    for (int rt = 0; rt < 3; ++rt)
#pragma unroll
      for (int ct = 0; ct < 4; ++ct) accB[rt][ct] = z4;

#pragma unroll
    for (int rt = 0; rt < 3; ++rt) {
      short8 afr[4];
#pragma unroll
      for (int k = 0; k < 4; ++k)
        afr[k] = *reinterpret_cast<const short8*>(
            wselB + (size_t)(wrb + rt * 16 + tt) * 128 + k * 32 + qq * 8);
#pragma unroll
      for (int ct = 0; ct < 4; ++ct) {
#pragma unroll
        for (int k = 0; k < 4; ++k) {
          const short8 bfr = *reinterpret_cast<const short8*>(
              &sm.u.xt[ct * 16 + tt][k * 32 + qq * 8]);
          accB[rt][ct] = __builtin_amdgcn_mfma_f32_16x16x32_bf16(afr[k], bfr, accB[rt][ct], 0, 0, 0);
        }
      }
    }
    __syncthreads();   // all xt reads done; fh overlay now safe

    if (isfB) {
#pragma unroll
      for (int rt = 0; rt < 3; ++rt)
#pragma unroll
        for (int ct = 0; ct < 4; ++ct)
#pragma unroll
          for (int rg = 0; rg < 4; ++rg)
            sm.u.fh[(wrb + rt * 16 + qq * 4 + rg) * 65 + ct * 16 + tt] =
                accB[rt][ct][rg] + biasB[rt][rg];
    }
  } else {
    // ---- fp32 fallback: R3 direct-global VALU GEMM ----
    const void*  wsel  = is_f ? f_w : v_w;
    const void*  bsel  = is_f ? f_b : v_b;
    const size_t wrow0 = (size_t)(is_f ? ty * 12 : ty * 12 - 96);
#pragma unroll
    for (int r = 0; r < 12; ++r) bias[r] = ld1<false>(bsel, wrow0 + r);
#pragma unroll
    for (int r = 0; r < 12; ++r)
#pragma unroll
      for (int j = 0; j < 4; ++j) acc[r][j] = 0.f;

    const size_t xbase = ((size_t)b * kCin) * kHW + hw0 + tx * 4;
    for (int i = 0; i < 128; i += 4) {
      float xv[4][4];
#pragma unroll
      for (int ci = 0; ci < 4; ++ci) ld4<false>(x, xbase + (size_t)(i + ci) * kHW, xv[ci]);
      float wvr[6][4];
#pragma unroll
      for (int r = 0; r < 6; ++r) ld4<false>(wsel, (wrow0 + r) * 128 + i, wvr[r]);
#pragma unroll
      for (int r = 0; r < 6; ++r)
#pragma unroll
        for (int ci = 0; ci < 4; ++ci)
#pragma unroll
          for (int j = 0; j < 4; ++j)
            acc[r][j] = fmaf(wvr[r][ci], xv[ci][j], acc[r][j]);
#pragma unroll
      for (int r = 0; r < 6; ++r) ld4<false>(wsel, (wrow0 + 6 + r) * 128 + i, wvr[r]);
#pragma unroll
      for (int r = 0; r < 6; ++r)
#pragma unroll
        for (int ci = 0; ci < 4; ++ci)
#pragma unroll
          for (int j = 0; j < 4; ++j)
            acc[6 + r][j] = fmaf(wvr[r][ci], xv[ci][j], acc[6 + r][j]);
    }
    if (is_f) {
#pragma unroll
      for (int r = 0; r < 12; ++r)
#pragma unroll
        for (int j = 0; j < 4; ++j)
          sm.u.fh[(ty * 12 + r) * 65 + tx * 4 + j] = acc[r][j] + bias[r];
    }
  }
  __syncthreads();

  // ---- phase B1: sim / sigmoid / argmax, stage (s, idx) into d_out ch 0..7 ----
  {
    float dm[4] = {0.f, 0.f, 0.f, 0.f};
    float n2 = 0.f;
#pragma unroll
    for (int c = 0; c < 24; ++c) {
      const float fc = sm.u.fh[(e * 24 + c) * 65 + tok];
      n2 += fc * fc;
      dm[0] += fc * sm.cn[0][c];
      dm[1] += fc * sm.cn[1][c];
      dm[2] += fc * sm.cn[2][c];
      dm[3] += fc * sm.cn[3][c];
    }
    const float inv = 1.f / fmaxf(sqrtf(n2), 1e-12f);
    float s[4];
#pragma unroll
    for (int m = 0; m < 4; ++m) {
      const float z = beta + alpha * dm[m] * inv;
      s[m] = 1.f / (1.f + __expf(-z));
    }
    float best = -1.f;
    int bi = 0;
#pragma unroll
    for (int m = 0; m < 4; ++m)
      if (s[m] > best) { best = s[m]; bi = m; }   // strict >: first max, like jnp.argmax

    const int hw = hw0 + tok;
    st1<BF>(out0, ((size_t)(b * 128 + e)) * kHW + hw, best);          // stage s
    st1<BF>(out0, ((size_t)(b * 128 + 4 + e)) * kHW + hw, (float)bi); // stage idx
    sm.s[e][tok]   = best;
    sm.idx[e][tok] = (unsigned char)bi;
    if (e == 0) {
      const int h = hw / kW;
      const int w = hw - h * kW;
      sm.q[tok] = (unsigned char)((h >= 56 ? 2 : 0) + (w >= 56 ? 1 : 0));
    }
  }
  __syncthreads();

  // ---- overwrite fh with v half (from registers) ----
  if constexpr (BF) {
    if (!isfB) {
#pragma unroll
      for (int rt = 0; rt < 3; ++rt)
#pragma unroll
        for (int ct = 0; ct < 4; ++ct)
#pragma unroll
          for (int rg = 0; rg < 4; ++rg)
            sm.u.fh[(wrb + rt * 16 + qq * 4 + rg) * 65 + ct * 16 + tt] =
                accB[rt][ct][rg] + biasB[rt][rg];
    }
  } else {
    if (!is_f) {
#pragma unroll
      for (int r = 0; r < 12; ++r)
#pragma unroll
        for (int j = 0; j < 4; ++j)
          sm.u.fh[((ty - 8) * 12 + r) * 65 + tx * 4 + j] = acc[r][j] + bias[r];
    }
  }
  __syncthreads();

  // ---- phase B2: block reduction over 64 tokens, 2 token-halves in parallel ----
  float agg_m[4]  = {0.f, 0.f, 0.f, 0.f};
  float pool_q[4] = {0.f, 0.f, 0.f, 0.f};
  float cacc = 0.f;
  if (tid < 192) {
    const int half = tid / 96;
    const int c    = tid - half * 96;
    const int eh   = c / 24;
    const int row0 = c * 65;
    const int t20  = half * 32;
    for (int k = 0; k < 32; ++k) {
      const int t2 = t20 + k;
      const float v = sm.u.fh[row0 + t2];
      const float s = sm.s[eh][t2];
      const int  mi = sm.idx[eh][t2];
      const int  q  = sm.q[t2];
      const float sv = s * v;
      agg_m[0]  += (mi == 0) ? sv : 0.f;
      agg_m[1]  += (mi == 1) ? sv : 0.f;
      agg_m[2]  += (mi == 2) ? sv : 0.f;
      agg_m[3]  += (mi == 3) ? sv : 0.f;
      pool_q[0] += (q == 0) ? v : 0.f;
      pool_q[1] += (q == 1) ? v : 0.f;
      pool_q[2] += (q == 2) ? v : 0.f;
      pool_q[3] += (q == 3) ? v : 0.f;
    }
    const int cc  = c % 24;
    const int bh  = b * 4 + eh;
#pragma unroll
    for (int m = 0; m < 4; ++m) {
      atomicAdd(&aggsum[(bh * 4 + m) * 24 + cc], agg_m[m]);
      atomicAdd(&vpool[(bh * 4 + m) * 24 + cc], pool_q[m]);
    }
  } else if (tid < 224) {
    const int p  = tid - 192;
    const int em = p >> 1;
    const int ce = em >> 2, cm = em & 3;
    const int t20 = (p & 1) * 32;
    for (int k = 0; k < 32; ++k) {
      const int t2 = t20 + k;
      cacc += (sm.idx[ce][t2] == cm) ? sm.s[ce][t2] : 0.f;
    }
    atomicAdd(&cnt[b * 16 + em], cacc);
  }
}

__global__ __launch_bounds__(256, 2) void cluster_main(
    const int* __restrict__ flag,
    const void* x, const void* f_w, const void* f_b, const void* v_w, const void* v_b,
    const void* sim_alpha, const void* sim_beta, const void* centers,
    void* out0, float* aggsum, float* vpool, float* cnt)
{
  __shared__ SMain sm;
  if (*flag)
    main_body<true>(sm, x, f_w, f_b, v_w, v_b, sim_alpha, sim_beta, centers, out0, aggsum, vpool, cnt);
  else
    main_body<false>(sm, x, f_w, f_b, v_w, v_b, sim_alpha, sim_beta, centers, out0, aggsum, vpool, cnt);
}

// ---------------------------------------------------------------------------
// Kernel 2 (ptab folded in): per block —
//   af[em][c] = (aggsum + vpool/3136) / (cnt + 1)
//   p[o*16 + e*4 + m] = sum_c proj_w[o][e*24+c] * af[e][m][c]
//   out[o][tok] = proj_b[o] + sum_e s_e(tok) * p[o][e][idx_e]
// 8-token x 16-channel tiles per thread: stores 128x2B -> 32x8B vectorized.
// NOTE barrier between s/idx loads and channel stores: with tiling, a token's
// staged s/idx (planes 0..7) is read by 8 threads while another thread
// overwrites those planes — block-local race without the barrier.
// ---------------------------------------------------------------------------
struct SOut {
  float af[384];
  float p[2048];   // [o][e*4+m]
  float pb[128];
};

template <bool BF>
__device__ __forceinline__ void out_body(
    SOut& so, const void* __restrict__ proj_w, const void* __restrict__ proj_b,
    const float* __restrict__ aggsum, const float* __restrict__ vpool,
    const float* __restrict__ cnt, void* __restrict__ out0)
{
  const int tid = threadIdx.x;
  const int b   = blockIdx.x / kGrps;
  const int grp = blockIdx.x % kGrps;

  for (int k = tid; k < 384; k += 256) {
    const int em = k / 24;
    so.af[k] = (aggsum[b * 384 + k] + vpool[b * 384 + k] * (1.f / 3136.f)) / (cnt[b * 16 + em] + 1.f);
  }
  if (tid < 128) so.pb[tid] = ld1<BF>(proj_b, tid);
  __syncthreads();
#pragma unroll
  for (int i = 0; i < 8; ++i) {
    const int g  = i * 256 + tid;      // g = o*16 + em
    const int o  = g >> 4;
    const int em = g & 15;
    const int e  = em >> 2;
    float a = 0.f;
#pragma unroll
    for (int c = 0; c < 24; ++c)
      a = fmaf(ld1<BF>(proj_w, (size_t)o * 96 + e * 24 + c), so.af[em * 24 + c], a);
    so.p[g] = a;
  }
  __syncthreads();

  const int tgi = tid & 31;          // 8-token group
  const int cg  = tid >> 5;          // 16-channel group (0..7)
  const int hw  = grp * 256 + tgi * 8;
  const size_t base = ((size_t)(b * 128)) * kHW + hw;

  float sv[4][8];
  int   mi[4][8];
  float ivh[8];
#pragma unroll
  for (int e2 = 0; e2 < 4; ++e2) {
    ld4<BF>(out0, base + (size_t)e2 * kHW,     &sv[e2][0]);
    ld4<BF>(out0, base + (size_t)e2 * kHW + 4, &sv[e2][4]);
    float iv[8];
    ld4<BF>(out0, base + (size_t)(4 + e2) * kHW,     &iv[0]);
    ld4<BF>(out0, base + (size_t)(4 + e2) * kHW + 4, &iv[4]);
#pragma unroll
    for (int j = 0; j < 8; ++j) {
      mi[e2][j] = (int)(iv[j] + 0.5f);
      if (e2 == 0) ivh[j] = iv[j];
    }
  }
  __syncthreads();   // ALL s/idx loads complete before any store to planes 0..127

  if (b == 0 && cg == 0) {
    // assignment map: head-0 idx of batch 0 (exact small-int in both dtypes)
    st4<BF>(out0, kOut1Off + hw,     &ivh[0]);
    st4<BF>(out0, kOut1Off + hw + 4, &ivh[4]);
  }

#pragma unroll
  for (int oi = 0; oi < 16; ++oi) {
    const int o = cg * 16 + oi;
    const float* pr  = &so.p[o * 16];
    const float  pbv = so.pb[o];
    float ov[8];
#pragma unroll
    for (int j = 0; j < 8; ++j) {
      float a = pbv;
      a = fmaf(sv[0][j], pr[ 0 + mi[0][j]], a);
      a = fmaf(sv[1][j], pr[ 4 + mi[1][j]], a);
      a = fmaf(sv[2][j], pr[ 8 + mi[2][j]], a);
      a = fmaf(sv[3][j], pr[12 + mi[3][j]], a);
      ov[j] = a;
    }
    st4<BF>(out0, base + (size_t)o * kHW,     &ov[0]);
    st4<BF>(out0, base + (size_t)o * kHW + 4, &ov[4]);
  }
}

__global__ __launch_bounds__(256) void cluster_out(
    const int* __restrict__ flag,
    const void* proj_w, const void* proj_b,
    const float* __restrict__ aggsum, const float* __restrict__ vpool,
    const float* __restrict__ cnt, void* out0)
{
  __shared__ SOut so;
  if (*flag) out_body<true>(so, proj_w, proj_b, aggsum, vpool, cnt, out0);
  else       out_body<false>(so, proj_w, proj_b, aggsum, vpool, cnt, out0);
}

}  // namespace

extern "C" void kernel_launch(void* const* d_in, const int* in_sizes, int n_in,
                              void* d_out, int out_size, void* d_ws, size_t ws_size,
                              hipStream_t stream) {
  const void* x         = d_in[0];
  const void* f_w       = d_in[1];
  const void* f_b       = d_in[2];
  const void* v_w       = d_in[3];
  const void* v_b       = d_in[4];
  const void* proj_w    = d_in[5];
  const void* proj_b    = d_in[6];
  const void* sim_alpha = d_in[7];
  const void* sim_beta  = d_in[8];
  const void* centers   = d_in[9];

  // ws layout: [0..15] bytes: dtype flag (int). Then floats:
  //   aggsum[6144] vpool[6144] cnt[256]
  int*   flag   = (int*)d_ws;
  float* fws    = (float*)((char*)d_ws + 16);
  float* aggsum = fws;
  float* vpool  = fws + 6144;
  float* cnt    = fws + 12288;

  // zero flag + accumulators (ws is poisoned 0xAA before every call)
  hipMemsetAsync(d_ws, 0, 16 + 12544 * sizeof(float), stream);

  detect_dtype<<<dim3(1), dim3(256), 0, stream>>>((const unsigned short*)f_w, flag);
  cluster_main<<<dim3(16 * kTiles), dim3(256), 0, stream>>>(
      flag, x, f_w, f_b, v_w, v_b, sim_alpha, sim_beta, centers,
      d_out, aggsum, vpool, cnt);
  cluster_out<<<dim3(16 * kGrps), dim3(256), 0, stream>>>(
      flag, proj_w, proj_b, aggsum, vpool, cnt, d_out);
}

// Round 7
// 440.940 us; speedup vs baseline: 1.1030x; 1.1030x over previous
//
#include <hip/hip_runtime.h>
#include <hip/hip_bf16.h>

namespace {

constexpr int kCin   = 128;
constexpr int kHW    = 12544;   // 112*112
constexpr int kW     = 112;
constexpr int kGrps  = 49;      // output kernel: 49 blocks * 256 tokens per image
constexpr int kTiles = 196;     // main kernel: 196 blocks * 64 tokens per image
constexpr size_t kOut1Off = (size_t)16 * 128 * kHW;  // element offset of assignment map

typedef __attribute__((ext_vector_type(8))) short short8;   // 8 bf16 = 4 VGPR (MFMA A/B frag)
typedef __attribute__((ext_vector_type(4))) float f32x4;    // MFMA C/D frag

__device__ __forceinline__ float bf2f(unsigned short u) {
  union { unsigned int i; float f; } v;
  v.i = ((unsigned int)u) << 16;
  return v.f;
}

__device__ __forceinline__ unsigned short f2bf(float f) {
  union { float f; unsigned int i; } v;
  v.f = f;
  unsigned int x = v.i;
  x += 0x7fffu + ((x >> 16) & 1u);   // RNE
  return (unsigned short)(x >> 16);
}

// ---- dtype-templated load/store helpers (BF=true: bf16, else fp32) ----
template <bool BF>
__device__ __forceinline__ float ld1(const void* p, size_t i) {
  if constexpr (BF) return bf2f(((const unsigned short*)p)[i]);
  else              return ((const float*)p)[i];
}
template <bool BF>
__device__ __forceinline__ void ld4(const void* p, size_t i, float o[4]) {
  if constexpr (BF) {
    const ushort4 u = *reinterpret_cast<const ushort4*>((const unsigned short*)p + i);
    o[0] = bf2f(u.x); o[1] = bf2f(u.y); o[2] = bf2f(u.z); o[3] = bf2f(u.w);
  } else {
    const float4 u = *reinterpret_cast<const float4*>((const float*)p + i);
    o[0] = u.x; o[1] = u.y; o[2] = u.z; o[3] = u.w;
  }
}
template <bool BF>
__device__ __forceinline__ void st1(void* p, size_t i, float v) {
  if constexpr (BF) ((unsigned short*)p)[i] = f2bf(v);
  else              ((float*)p)[i] = v;
}
template <bool BF>
__device__ __forceinline__ void st4(void* p, size_t i, const float v[4]) {
  if constexpr (BF) {
    ushort4 u;
    u.x = f2bf(v[0]); u.y = f2bf(v[1]); u.z = f2bf(v[2]); u.w = f2bf(v[3]);
    *reinterpret_cast<ushort4*>((unsigned short*)p + i) = u;
  } else {
    float4 u;
    u.x = v[0]; u.y = v[1]; u.z = v[2]; u.w = v[3];
    *reinterpret_cast<float4*>((float*)p + i) = u;
  }
}

// ---------------------------------------------------------------------------
// Kernel 0: detect input dtype. bf16 f_w values are ~N(0, 0.09): none exceed 4.
// fp32 f_w read as bf16 pairs: ~25% of ushorts are mantissa garbage with
// uniform-random exponent -> |v|>4 for ~half of those. flag=1 means bf16.
// ---------------------------------------------------------------------------
__global__ void detect_dtype(const unsigned short* __restrict__ fw, int* __restrict__ flag) {
  __shared__ int cnt_s;
  if (threadIdx.x == 0) cnt_s = 0;
  __syncthreads();
  int c = 0;
  for (int i = threadIdx.x; i < 4096; i += 256) {
    const float v = bf2f(fw[i]);
    if (fabsf(v) > 4.0f) ++c;
  }
  atomicAdd(&cnt_s, c);
  __syncthreads();
  if (threadIdx.x == 0) flag[0] = (cnt_s > 100) ? 0 : 1;
}

// ---------------------------------------------------------------------------
// Kernel 1: ONE 64-token tile per block (grid 16*196=3136).
// bf16 path: conv on matrix cores (mfma_f32_16x16x32_bf16, verified R6).
// NO GLOBAL ATOMICS: R6 showed duration (~320us) invariant to occupancy,
// staging, and compute engine, with all visible pipes <35% busy — the
// remaining suspect whose arithmetic matches is device-scope atomic
// serialization (28K wave-atomics x ~25cyc ~= 292us). Each block now
// LDS-combines its two token-halves and writes a 784-float per-tile partial
// (non-atomic, coalesced) to ws; cluster_red tree-reduces 196 tiles/batch.
// ---------------------------------------------------------------------------
struct alignas(16) SMain {
  union {
    unsigned short xt[64][136];  // 17408 B: X^T (bf16 MFMA path only)
    float fh[96 * 65];           // 24960 B: f rows (B1), v rows (B2), then red scratch
  } u;
  float cn[4][24];
  float s[4][64];
  unsigned char idx[4][64];
  unsigned char q[64];
};

template <bool BF>
__device__ __forceinline__ void main_body(
    SMain& sm,
    const void* __restrict__ x,  const void* __restrict__ f_w, const void* __restrict__ f_b,
    const void* __restrict__ v_w, const void* __restrict__ v_b,
    const void* __restrict__ sim_alpha, const void* __restrict__ sim_beta,
    const void* __restrict__ centers,
    void* __restrict__ out0, float* __restrict__ partial)
{
  const int tid  = threadIdx.x;
  const int b    = blockIdx.x / kTiles;
  const int tile = blockIdx.x % kTiles;
  const int hw0  = tile * 64;

  if (tid < 4) {
    float cv[24];
    float n2 = 0.f;
#pragma unroll
    for (int c = 0; c < 24; ++c) { cv[c] = ld1<BF>(centers, tid * 24 + c); n2 += cv[c] * cv[c]; }
    const float inv = 1.f / fmaxf(sqrtf(n2), 1e-12f);
#pragma unroll
    for (int c = 0; c < 24; ++c) sm.cn[tid][c] = cv[c] * inv;
  }
  const float alpha = ld1<BF>(sim_alpha, 0);
  const float beta  = ld1<BF>(sim_beta, 0);

  const int e   = tid >> 6;
  const int tok = tid & 63;

  // ---- BF (MFMA) path state ----
  const int lane = tid & 63;
  const int wv   = tid >> 6;       // wave 0..3
  const int qq   = lane >> 4;      // 0..3
  const int tt   = lane & 15;
  f32x4 accB[3][4];
  float biasB[3][4];
  int   wrb = 0;
  bool  isfB = true;

  // ---- fp32 (VALU) path state ----
  const int ty = tid >> 4;
  const int tx = tid & 15;
  const bool is_f = (ty < 8);
  float acc[12][4];
  float bias[12];

  if constexpr (BF) {
    // ---- stage X^T: xt[tok][ch], 128 ch, stride 136 (16B-aligned rows) ----
#pragma unroll
    for (int s5 = 0; s5 < 8; ++s5) {
      const int id2 = tid + s5 * 256;      // 0..2047: 128 ch x 16 token-groups
      const int ch  = id2 >> 4;
      const int tg  = id2 & 15;
      const ushort4 u4 = *reinterpret_cast<const ushort4*>(
          (const unsigned short*)x + ((size_t)b * kCin + ch) * kHW + hw0 + tg * 4);
      sm.u.xt[tg * 4 + 0][ch] = u4.x;
      sm.u.xt[tg * 4 + 1][ch] = u4.y;
      sm.u.xt[tg * 4 + 2][ch] = u4.z;
      sm.u.xt[tg * 4 + 3][ch] = u4.w;
    }
    const int wbase = wv * 48;
    isfB = (wv < 2);
    const unsigned short* wselB = (const unsigned short*)(isfB ? f_w : v_w);
    const void* bselB = isfB ? f_b : v_b;
    wrb = isfB ? wbase : wbase - 96;
#pragma unroll
    for (int rt = 0; rt < 3; ++rt)
#pragma unroll
      for (int rg = 0; rg < 4; ++rg)
        biasB[rt][rg] = ld1<true>(bselB, (size_t)(wrb + rt * 16 + qq * 4 + rg));
    __syncthreads();

    const f32x4 z4 = {0.f, 0.f, 0.f, 0.f};
#pragma unroll
    for (int rt = 0; rt < 3; ++rt)
#pragma unroll
      for (int ct = 0; ct < 4; ++ct) accB[rt][ct] = z4;

#pragma unroll
    for (int rt = 0; rt < 3; ++rt) {
      short8 afr[4];
#pragma unroll
      for (int k = 0; k < 4; ++k)
        afr[k] = *reinterpret_cast<const short8*>(
            wselB + (size_t)(wrb + rt * 16 + tt) * 128 + k * 32 + qq * 8);
#pragma unroll
      for (int ct = 0; ct < 4; ++ct) {
#pragma unroll
        for (int k = 0; k < 4; ++k) {
          const short8 bfr = *reinterpret_cast<const short8*>(
              &sm.u.xt[ct * 16 + tt][k * 32 + qq * 8]);
          accB[rt][ct] = __builtin_amdgcn_mfma_f32_16x16x32_bf16(afr[k], bfr, accB[rt][ct], 0, 0, 0);
        }
      }
    }
    __syncthreads();   // all xt reads done; fh overlay now safe

    if (isfB) {
#pragma unroll
      for (int rt = 0; rt < 3; ++rt)
#pragma unroll
        for (int ct = 0; ct < 4; ++ct)
#pragma unroll
          for (int rg = 0; rg < 4; ++rg)
            sm.u.fh[(wrb + rt * 16 + qq * 4 + rg) * 65 + ct * 16 + tt] =
                accB[rt][ct][rg] + biasB[rt][rg];
    }
  } else {
    // ---- fp32 fallback: R3 direct-global VALU GEMM ----
    const void*  wsel  = is_f ? f_w : v_w;
    const void*  bsel  = is_f ? f_b : v_b;
    const size_t wrow0 = (size_t)(is_f ? ty * 12 : ty * 12 - 96);
#pragma unroll
    for (int r = 0; r < 12; ++r) bias[r] = ld1<false>(bsel, wrow0 + r);
#pragma unroll
    for (int r = 0; r < 12; ++r)
#pragma unroll
      for (int j = 0; j < 4; ++j) acc[r][j] = 0.f;

    const size_t xbase = ((size_t)b * kCin) * kHW + hw0 + tx * 4;
    for (int i = 0; i < 128; i += 4) {
      float xv[4][4];
#pragma unroll
      for (int ci = 0; ci < 4; ++ci) ld4<false>(x, xbase + (size_t)(i + ci) * kHW, xv[ci]);
      float wvr[6][4];
#pragma unroll
      for (int r = 0; r < 6; ++r) ld4<false>(wsel, (wrow0 + r) * 128 + i, wvr[r]);
#pragma unroll
      for (int r = 0; r < 6; ++r)
#pragma unroll
        for (int ci = 0; ci < 4; ++ci)
#pragma unroll
          for (int j = 0; j < 4; ++j)
            acc[r][j] = fmaf(wvr[r][ci], xv[ci][j], acc[r][j]);
#pragma unroll
      for (int r = 0; r < 6; ++r) ld4<false>(wsel, (wrow0 + 6 + r) * 128 + i, wvr[r]);
#pragma unroll
      for (int r = 0; r < 6; ++r)
#pragma unroll
        for (int ci = 0; ci < 4; ++ci)
#pragma unroll
          for (int j = 0; j < 4; ++j)
            acc[6 + r][j] = fmaf(wvr[r][ci], xv[ci][j], acc[6 + r][j]);
    }
    if (is_f) {
#pragma unroll
      for (int r = 0; r < 12; ++r)
#pragma unroll
        for (int j = 0; j < 4; ++j)
          sm.u.fh[(ty * 12 + r) * 65 + tx * 4 + j] = acc[r][j] + bias[r];
    }
  }
  __syncthreads();

  // ---- phase B1: sim / sigmoid / argmax, stage (s, idx) into d_out ch 0..7 ----
  {
    float dm[4] = {0.f, 0.f, 0.f, 0.f};
    float n2 = 0.f;
#pragma unroll
    for (int c = 0; c < 24; ++c) {
      const float fc = sm.u.fh[(e * 24 + c) * 65 + tok];
      n2 += fc * fc;
      dm[0] += fc * sm.cn[0][c];
      dm[1] += fc * sm.cn[1][c];
      dm[2] += fc * sm.cn[2][c];
      dm[3] += fc * sm.cn[3][c];
    }
    const float inv = 1.f / fmaxf(sqrtf(n2), 1e-12f);
    float s[4];
#pragma unroll
    for (int m = 0; m < 4; ++m) {
      const float z = beta + alpha * dm[m] * inv;
      s[m] = 1.f / (1.f + __expf(-z));
    }
    float best = -1.f;
    int bi = 0;
#pragma unroll
    for (int m = 0; m < 4; ++m)
      if (s[m] > best) { best = s[m]; bi = m; }   // strict >: first max, like jnp.argmax

    const int hw = hw0 + tok;
    st1<BF>(out0, ((size_t)(b * 128 + e)) * kHW + hw, best);          // stage s
    st1<BF>(out0, ((size_t)(b * 128 + 4 + e)) * kHW + hw, (float)bi); // stage idx
    sm.s[e][tok]   = best;
    sm.idx[e][tok] = (unsigned char)bi;
    if (e == 0) {
      const int h = hw / kW;
      const int w = hw - h * kW;
      sm.q[tok] = (unsigned char)((h >= 56 ? 2 : 0) + (w >= 56 ? 1 : 0));
    }
  }
  __syncthreads();

  // ---- overwrite fh with v half (from registers) ----
  if constexpr (BF) {
    if (!isfB) {
#pragma unroll
      for (int rt = 0; rt < 3; ++rt)
#pragma unroll
        for (int ct = 0; ct < 4; ++ct)
#pragma unroll
          for (int rg = 0; rg < 4; ++rg)
            sm.u.fh[(wrb + rt * 16 + qq * 4 + rg) * 65 + ct * 16 + tt] =
                accB[rt][ct][rg] + biasB[rt][rg];
    }
  } else {
    if (!is_f) {
#pragma unroll
      for (int r = 0; r < 12; ++r)
#pragma unroll
        for (int j = 0; j < 4; ++j)
          sm.u.fh[((ty - 8) * 12 + r) * 65 + tx * 4 + j] = acc[r][j] + bias[r];
    }
  }
  __syncthreads();

  // ---- phase B2: block reduction over 64 tokens, 2 token-halves in parallel ----
  float agg_m[4]  = {0.f, 0.f, 0.f, 0.f};
  float pool_q[4] = {0.f, 0.f, 0.f, 0.f};
  float cacc = 0.f;
  if (tid < 192) {
    const int half = tid / 96;
    const int c    = tid - half * 96;
    const int eh   = c / 24;
    const int row0 = c * 65;
    const int t20  = half * 32;
    for (int k = 0; k < 32; ++k) {
      const int t2 = t20 + k;
      const float v = sm.u.fh[row0 + t2];
      const float s = sm.s[eh][t2];
      const int  mi = sm.idx[eh][t2];
      const int  q  = sm.q[t2];
      const float sv = s * v;
      agg_m[0]  += (mi == 0) ? sv : 0.f;
      agg_m[1]  += (mi == 1) ? sv : 0.f;
      agg_m[2]  += (mi == 2) ? sv : 0.f;
      agg_m[3]  += (mi == 3) ? sv : 0.f;
      pool_q[0] += (q == 0) ? v : 0.f;
      pool_q[1] += (q == 1) ? v : 0.f;
      pool_q[2] += (q == 2) ? v : 0.f;
      pool_q[3] += (q == 3) ? v : 0.f;
    }
  } else if (tid < 224) {
    const int p  = tid - 192;
    const int em = p >> 1;
    const int ce = em >> 2, cm = em & 3;
    const int t20 = (p & 1) * 32;
    for (int k = 0; k < 32; ++k) {
      const int t2 = t20 + k;
      cacc += (sm.idx[ce][t2] == cm) ? sm.s[ce][t2] : 0.f;
    }
  }
  __syncthreads();   // all fh/s/idx reads complete before fh is reused as scratch

  // ---- combine halves in LDS, write per-tile partial (NO global atomics) ----
  float* red = sm.u.fh;   // scratch: [2][96][8] + [32] = 1568 floats << 6240
  if (tid < 192) {
    const int half = tid / 96;
    const int c    = tid - half * 96;
    float* r = &red[(half * 96 + c) * 8];
    r[0] = agg_m[0]; r[1] = agg_m[1]; r[2] = agg_m[2]; r[3] = agg_m[3];
    r[4] = pool_q[0]; r[5] = pool_q[1]; r[6] = pool_q[2]; r[7] = pool_q[3];
  } else if (tid < 224) {
    red[1536 + (tid - 192)] = cacc;
  }
  __syncthreads();

  float* pt = &partial[(size_t)blockIdx.x * 784];
  if (tid < 96) {
    const int c = tid;
#pragma unroll
    for (int m = 0; m < 4; ++m)
      pt[m * 96 + c] = red[c * 8 + m] + red[(96 + c) * 8 + m];
#pragma unroll
    for (int q2 = 0; q2 < 4; ++q2)
      pt[384 + q2 * 96 + c] = red[c * 8 + 4 + q2] + red[(96 + c) * 8 + 4 + q2];
  } else if (tid < 112) {
    const int em = tid - 96;
    pt[768 + em] = red[1536 + 2 * em] + red[1536 + 2 * em + 1];
  }
}

__global__ __launch_bounds__(256, 2) void cluster_main(
    const int* __restrict__ flag,
    const void* x, const void* f_w, const void* f_b, const void* v_w, const void* v_b,
    const void* sim_alpha, const void* sim_beta, const void* centers,
    void* out0, float* __restrict__ partial)
{
  __shared__ SMain sm;
  if (*flag)
    main_body<true>(sm, x, f_w, f_b, v_w, v_b, sim_alpha, sim_beta, centers, out0, partial);
  else
    main_body<false>(sm, x, f_w, f_b, v_w, v_b, sim_alpha, sim_beta, centers, out0, partial);
}

// ---------------------------------------------------------------------------
// Kernel 1.5: tree-reduce per-tile partials over 196 tiles into final
// aggsum/vpool/cnt layouts. One thread per (b, v): coalesced stride-784 rows.
// ---------------------------------------------------------------------------
__global__ void cluster_red(const float* __restrict__ partial,
                            float* __restrict__ aggsum, float* __restrict__ vpool,
                            float* __restrict__ cnt) {
  const int g = blockIdx.x * 256 + threadIdx.x;
  if (g >= 16 * 784) return;
  const int b = g / 784;
  const int v = g - b * 784;
  const float* base = partial + (size_t)b * kTiles * 784 + v;
  float s = 0.f;
#pragma unroll 4
  for (int t = 0; t < kTiles; ++t) s += base[(size_t)t * 784];
  if (v < 384) {
    const int m = v / 96, c = v - m * 96;
    const int eh = c / 24, cc = c - eh * 24;
    aggsum[b * 384 + (eh * 4 + m) * 24 + cc] = s;
  } else if (v < 768) {
    const int q = (v - 384) / 96, c = (v - 384) - q * 96;
    const int eh = c / 24, cc = c - eh * 24;
    vpool[b * 384 + (eh * 4 + q) * 24 + cc] = s;
  } else {
    cnt[b * 16 + (v - 768)] = s;
  }
}

// ---------------------------------------------------------------------------
// Kernel 2 (ptab folded in): per block —
//   af[em][c] = (aggsum + vpool/3136) / (cnt + 1)
//   p[o*16 + e*4 + m] = sum_c proj_w[o][e*24+c] * af[e][m][c]
//   out[o][tok] = proj_b[o] + sum_e s_e(tok) * p[o][e][idx_e]
// 8-token x 16-channel tiles per thread: stores 128x2B -> 32x8B vectorized.
// Barrier between the s/idx loads and channel stores (cross-thread race).
// ---------------------------------------------------------------------------
struct SOut {
  float af[384];
  float p[2048];   // [o][e*4+m]
  float pb[128];
};

template <bool BF>
__device__ __forceinline__ void out_body(
    SOut& so, const void* __restrict__ proj_w, const void* __restrict__ proj_b,
    const float* __restrict__ aggsum, const float* __restrict__ vpool,
    const float* __restrict__ cnt, void* __restrict__ out0)
{
  const int tid = threadIdx.x;
  const int b   = blockIdx.x / kGrps;
  const int grp = blockIdx.x % kGrps;

  for (int k = tid; k < 384; k += 256) {
    const int em = k / 24;
    so.af[k] = (aggsum[b * 384 + k] + vpool[b * 384 + k] * (1.f / 3136.f)) / (cnt[b * 16 + em] + 1.f);
  }
  if (tid < 128) so.pb[tid] = ld1<BF>(proj_b, tid);
  __syncthreads();
#pragma unroll
  for (int i = 0; i < 8; ++i) {
    const int g  = i * 256 + tid;      // g = o*16 + em
    const int o  = g >> 4;
    const int em = g & 15;
    const int e  = em >> 2;
    float a = 0.f;
#pragma unroll
    for (int c = 0; c < 24; ++c)
      a = fmaf(ld1<BF>(proj_w, (size_t)o * 96 + e * 24 + c), so.af[em * 24 + c], a);
    so.p[g] = a;
  }
  __syncthreads();

  const int tgi = tid & 31;          // 8-token group
  const int cg  = tid >> 5;          // 16-channel group (0..7)
  const int hw  = grp * 256 + tgi * 8;
  const size_t base = ((size_t)(b * 128)) * kHW + hw;

  float sv[4][8];
  int   mi[4][8];
  float ivh[8];
#pragma unroll
  for (int e2 = 0; e2 < 4; ++e2) {
    ld4<BF>(out0, base + (size_t)e2 * kHW,     &sv[e2][0]);
    ld4<BF>(out0, base + (size_t)e2 * kHW + 4, &sv[e2][4]);
    float iv[8];
    ld4<BF>(out0, base + (size_t)(4 + e2) * kHW,     &iv[0]);
    ld4<BF>(out0, base + (size_t)(4 + e2) * kHW + 4, &iv[4]);
#pragma unroll
    for (int j = 0; j < 8; ++j) {
      mi[e2][j] = (int)(iv[j] + 0.5f);
      if (e2 == 0) ivh[j] = iv[j];
    }
  }
  __syncthreads();   // ALL s/idx loads complete before any store to planes 0..127

  if (b == 0 && cg == 0) {
    // assignment map: head-0 idx of batch 0 (exact small-int in both dtypes)
    st4<BF>(out0, kOut1Off + hw,     &ivh[0]);
    st4<BF>(out0, kOut1Off + hw + 4, &ivh[4]);
  }

#pragma unroll
  for (int oi = 0; oi < 16; ++oi) {
    const int o = cg * 16 + oi;
    const float* pr  = &so.p[o * 16];
    const float  pbv = so.pb[o];
    float ov[8];
#pragma unroll
    for (int j = 0; j < 8; ++j) {
      float a = pbv;
      a = fmaf(sv[0][j], pr[ 0 + mi[0][j]], a);
      a = fmaf(sv[1][j], pr[ 4 + mi[1][j]], a);
      a = fmaf(sv[2][j], pr[ 8 + mi[2][j]], a);
      a = fmaf(sv[3][j], pr[12 + mi[3][j]], a);
      ov[j] = a;
    }
    st4<BF>(out0, base + (size_t)o * kHW,     &ov[0]);
    st4<BF>(out0, base + (size_t)o * kHW + 4, &ov[4]);
  }
}

__global__ __launch_bounds__(256) void cluster_out(
    const int* __restrict__ flag,
    const void* proj_w, const void* proj_b,
    const float* __restrict__ aggsum, const float* __restrict__ vpool,
    const float* __restrict__ cnt, void* out0)
{
  __shared__ SOut so;
  if (*flag) out_body<true>(so, proj_w, proj_b, aggsum, vpool, cnt, out0);
  else       out_body<false>(so, proj_w, proj_b, aggsum, vpool, cnt, out0);
}

}  // namespace

extern "C" void kernel_launch(void* const* d_in, const int* in_sizes, int n_in,
                              void* d_out, int out_size, void* d_ws, size_t ws_size,
                              hipStream_t stream) {
  const void* x         = d_in[0];
  const void* f_w       = d_in[1];
  const void* f_b       = d_in[2];
  const void* v_w       = d_in[3];
  const void* v_b       = d_in[4];
  const void* proj_w    = d_in[5];
  const void* proj_b    = d_in[6];
  const void* sim_alpha = d_in[7];
  const void* sim_beta  = d_in[8];
  const void* centers   = d_in[9];

  // ws layout: [0..15] bytes: dtype flag (int). Then floats:
  //   aggsum[6144] vpool[6144] cnt[256] partial[3136*784]  -> ~9.9 MB total.
  // Every word is fully written before it is read (flag by detect_dtype,
  // partial by cluster_main, aggsum/vpool/cnt by cluster_red) -> no memset.
  int*   flag    = (int*)d_ws;
  float* fws     = (float*)((char*)d_ws + 16);
  float* aggsum  = fws;
  float* vpool   = fws + 6144;
  float* cnt     = fws + 12288;
  float* partial = fws + 12544;

  detect_dtype<<<dim3(1), dim3(256), 0, stream>>>((const unsigned short*)f_w, flag);
  cluster_main<<<dim3(16 * kTiles), dim3(256), 0, stream>>>(
      flag, x, f_w, f_b, v_w, v_b, sim_alpha, sim_beta, centers,
      d_out, partial);
  cluster_red<<<dim3(49), dim3(256), 0, stream>>>(partial, aggsum, vpool, cnt);
  cluster_out<<<dim3(16 * kGrps), dim3(256), 0, stream>>>(
      flag, proj_w, proj_b, aggsum, vpool, cnt, d_out);
}